// Round 6
// baseline (327.389 us; speedup 1.0000x reference)
//
#include <hip/hip_runtime.h>
#include <math.h>

namespace {
constexpr int NB = 4;       // batch
constexpr int NN = 2048;    // sequence
constexpr int FD = 1024;    // feature dim
constexpr int DE = 128;     // energy dim
constexpr int BN = NB * NN; // 8192 rows total

// ---- workspace layout (f32 units). Total 18,923,520 f32 = 75.7 MB.
// Phase A overlays inside the base region:
//   [0 .. 4,194,304)          partQ [4][8192][128] f32
//   [4,194,304 .. 8,388,608)  partK
//   [8,388,608 .. 12,582,912) Fh_sw (8.4M ushort, frag-tiled)
//   [12,582,912 .. 16,777,216) Fl_sw
// QKHL region (after base): Qh,Ql,Kh,Kl frag-tiled bf16 (4 x 1,048,576 ushort)
//   overlaid during phase A by Wsw (4 x 131,072 ushort)
constexpr size_t BASE_OFF  = 0;
constexpr size_t PARTQ_OFF = 0;
constexpr size_t PARTK_OFF = 4194304;
constexpr size_t FH_OFF    = 8388608;
constexpr size_t FL_OFF    = 12582912;
constexpr size_t QKHL_OFF  = 16777216;
constexpr size_t C_OFF     = QKHL_OFF + 2097152;   // 5 x [BN] charges
constexpr size_t R_OFF     = C_OFF + 5 * (size_t)BN;
}

typedef __attribute__((ext_vector_type(8))) short bf16x8;
typedef __attribute__((ext_vector_type(4))) float f32x4;

__device__ __forceinline__ unsigned short bf16_hi(float x) {
    unsigned u = __float_as_uint(x);
    unsigned r = (u + 0x7fffu + ((u >> 16) & 1u)) >> 16;
    return (unsigned short)r;
}
__device__ __forceinline__ float bf16_val(unsigned short h) {
    return __uint_as_float((unsigned)h << 16);
}

// Frag-tile layout: tile(row0=16 rows, k0=32 k) -> 64 lanes x 8 bf16, 1KB
// contiguous. lane = quad*16 + l16 holds (row = row0+l16, k = k0+quad*8+j).
// Identical mapping serves both A and B operands of mfma_f32_16x16x32_bf16.

// ---------------------------------------------------------------------------
// C1: F fp32 -> Fh_sw, Fl_sw (split hi/lo, frag-tiled).
// One thread per (tile, lane): 8 f32 each -> BN*FD/8/256 = 4096 blocks.
__global__ __launch_bounds__(256) void convert_F(
        const float* __restrict__ feat, unsigned short* __restrict__ Fh,
        unsigned short* __restrict__ Fl) {
    const int g = blockIdx.x * 256 + threadIdx.x;
    const int tile = g >> 6, lane = g & 63;
    const int tr = tile >> 5, fc = tile & 31;          // tr: 512 row-tiles, fc: 32 k-tiles
    const int row = tr * 16 + (lane & 15);
    const int f0 = fc * 32 + (lane >> 4) * 8;
    const float* src = &feat[(size_t)row * FD + f0];
    ushort4 h0, l0, h1, l1;
    float4 a = *(const float4*)src;
    float4 b = *(const float4*)(src + 4);
    h0.x = bf16_hi(a.x); l0.x = bf16_hi(a.x - bf16_val(h0.x));
    h0.y = bf16_hi(a.y); l0.y = bf16_hi(a.y - bf16_val(h0.y));
    h0.z = bf16_hi(a.z); l0.z = bf16_hi(a.z - bf16_val(h0.z));
    h0.w = bf16_hi(a.w); l0.w = bf16_hi(a.w - bf16_val(h0.w));
    h1.x = bf16_hi(b.x); l1.x = bf16_hi(b.x - bf16_val(h1.x));
    h1.y = bf16_hi(b.y); l1.y = bf16_hi(b.y - bf16_val(h1.y));
    h1.z = bf16_hi(b.z); l1.z = bf16_hi(b.z - bf16_val(h1.z));
    h1.w = bf16_hi(b.w); l1.w = bf16_hi(b.w - bf16_val(h1.w));
    const size_t dst = (size_t)tile * 512 + lane * 8;
    *(ushort4*)&Fh[dst] = h0; *(ushort4*)&Fh[dst + 4] = h1;
    *(ushort4*)&Fl[dst] = l0; *(ushort4*)&Fl[dst + 4] = l1;
}

// ---------------------------------------------------------------------------
// C2: W [f][e] fp32 -> frag-tiled hi/lo (tile = 16 e x 32 f).
__global__ __launch_bounds__(256) void convert_W(
        const float* __restrict__ Wq, const float* __restrict__ Wk,
        unsigned short* __restrict__ Wqh, unsigned short* __restrict__ Wql,
        unsigned short* __restrict__ Wkh, unsigned short* __restrict__ Wkl) {
    const int g = blockIdx.x * 256 + threadIdx.x;
    const int tile = g >> 6, lane = g & 63;
    const int ec = tile >> 5, fc = tile & 31;
    const int e = ec * 16 + (lane & 15);
    const int f0 = fc * 32 + (lane >> 4) * 8;
    const float* W = blockIdx.y ? Wk : Wq;
    unsigned short* Th = blockIdx.y ? Wkh : Wqh;
    unsigned short* Tl = blockIdx.y ? Wkl : Wql;
    unsigned short hh[8], ll[8];
    #pragma unroll
    for (int j = 0; j < 8; ++j) {
        float v = W[(size_t)(f0 + j) * DE + e];
        hh[j] = bf16_hi(v); ll[j] = bf16_hi(v - bf16_val(hh[j]));
    }
    const size_t dst = (size_t)tile * 512 + lane * 8;
    *(ushort4*)&Th[dst]     = make_ushort4(hh[0], hh[1], hh[2], hh[3]);
    *(ushort4*)&Th[dst + 4] = make_ushort4(hh[4], hh[5], hh[6], hh[7]);
    *(ushort4*)&Tl[dst]     = make_ushort4(ll[0], ll[1], ll[2], ll[3]);
    *(ushort4*)&Tl[dst + 4] = make_ushort4(ll[4], ll[5], ll[6], ll[7]);
}

// ---------------------------------------------------------------------------
// Kc: c0 = sigmoid(F @ cw + cb); also zero received.
__global__ __launch_bounds__(256) void charge_init(
        const float* __restrict__ feat, const float* __restrict__ cw,
        const float* __restrict__ cb, float* __restrict__ c0,
        float* __restrict__ received) {
    const int wave = threadIdx.x >> 6, lane = threadIdx.x & 63;
    const int r = blockIdx.x * 4 + wave;
    const float* fr = feat + (size_t)r * FD;
    float s = 0.f;
    #pragma unroll
    for (int k = 0; k < 16; ++k) { int f = lane + 64 * k; s += fr[f] * cw[f]; }
    for (int off = 32; off > 0; off >>= 1) s += __shfl_xor(s, off);
    if (lane == 0) {
        float x = s + cb[0];
        c0[r] = 1.f / (1.f + __expf(-x));
        received[r] = 0.f;
    }
}

// ---------------------------------------------------------------------------
// K0: split-bf16 MFMA projection, frag-tiled inputs (all loads coalesced 1KB).
__global__ __launch_bounds__(256) void qk_mfma(
        const unsigned short* __restrict__ Fh, const unsigned short* __restrict__ Fl,
        const unsigned short* __restrict__ Wqh, const unsigned short* __restrict__ Wql,
        const unsigned short* __restrict__ Wkh, const unsigned short* __restrict__ Wkl,
        float* __restrict__ partQ, float* __restrict__ partK) {
    const int tid = threadIdx.x;
    const int w = tid >> 6, lane = tid & 63;
    const int quad = lane >> 4, l16 = lane & 15;
    const int kc = blockIdx.x;
    const int tr0 = blockIdx.y * 4;             // row-tile base (64 rows)
    const unsigned short* Bh = (w < 2) ? Wqh : Wkh;
    const unsigned short* Bl = (w < 2) ? Wql : Wkl;
    const int ec0 = (w & 1) * 4;
    float* part = ((w < 2) ? partQ : partK) + (size_t)kc * BN * DE;

    f32x4 acc[4][4];
    #pragma unroll
    for (int a = 0; a < 4; ++a)
        #pragma unroll
        for (int c = 0; c < 4; ++c) acc[a][c] = (f32x4){0.f, 0.f, 0.f, 0.f};

    #pragma unroll 2
    for (int ch = 0; ch < 8; ++ch) {
        const int fc = kc * 8 + ch;             // k-tile index (32 f each)
        bf16x8 aH[4], aL[4];
        #pragma unroll
        for (int rt = 0; rt < 4; ++rt) {
            const size_t off = ((size_t)((tr0 + rt) * 32 + fc) * 64 + lane) * 8;
            aH[rt] = *(const bf16x8*)&Fh[off];
            aL[rt] = *(const bf16x8*)&Fl[off];
        }
        #pragma unroll
        for (int ct = 0; ct < 4; ++ct) {
            const size_t off = ((size_t)((ec0 + ct) * 32 + fc) * 64 + lane) * 8;
            bf16x8 bH = *(const bf16x8*)&Bh[off];
            bf16x8 bL = *(const bf16x8*)&Bl[off];
            #pragma unroll
            for (int rt = 0; rt < 4; ++rt) {
                acc[rt][ct] = __builtin_amdgcn_mfma_f32_16x16x32_bf16(aH[rt], bH, acc[rt][ct], 0, 0, 0);
                acc[rt][ct] = __builtin_amdgcn_mfma_f32_16x16x32_bf16(aH[rt], bL, acc[rt][ct], 0, 0, 0);
                acc[rt][ct] = __builtin_amdgcn_mfma_f32_16x16x32_bf16(aL[rt], bH, acc[rt][ct], 0, 0, 0);
            }
        }
    }
    #pragma unroll
    for (int rt = 0; rt < 4; ++rt)
        #pragma unroll
        for (int ct = 0; ct < 4; ++ct)
            #pragma unroll
            for (int reg = 0; reg < 4; ++reg) {
                const int row = (tr0 + rt) * 16 + quad * 4 + reg;
                const int e = (ec0 + ct) * 16 + l16;
                part[(size_t)row * DE + e] = acc[rt][ct][reg];
            }
}

// ---------------------------------------------------------------------------
// R0: sum 4 K-chunk partials, write frag-tiled bf16 hi/lo Q/K (global row tiles).
__global__ __launch_bounds__(256) void qk_reduce(
        const float* __restrict__ partQ, const float* __restrict__ partK,
        unsigned short* __restrict__ Qh, unsigned short* __restrict__ Ql,
        unsigned short* __restrict__ Kh, unsigned short* __restrict__ Kl) {
    const size_t i4 = ((size_t)blockIdx.x * 256 + threadIdx.x) * 4;
    float4 q = {0.f, 0.f, 0.f, 0.f}, k = {0.f, 0.f, 0.f, 0.f};
    #pragma unroll
    for (int c = 0; c < 4; ++c) {
        float4 a = *(const float4*)&partQ[(size_t)c * BN * DE + i4];
        float4 b = *(const float4*)&partK[(size_t)c * BN * DE + i4];
        q.x += a.x; q.y += a.y; q.z += a.z; q.w += a.w;
        k.x += b.x; k.y += b.y; k.z += b.z; k.w += b.w;
    }
    const int row = (int)(i4 >> 7);
    const int k0  = (int)(i4 & 127);
    const int kc = k0 >> 5, quad = (k0 >> 3) & 3, j = k0 & 7;   // j in {0,4}
    const int lane = quad * 16 + (row & 15);
    const size_t dst = ((size_t)((row >> 4) * 4 + kc) * 64 + lane) * 8 + j;
    ushort4 h, l;
    h.x = bf16_hi(q.x); l.x = bf16_hi(q.x - bf16_val(h.x));
    h.y = bf16_hi(q.y); l.y = bf16_hi(q.y - bf16_val(h.y));
    h.z = bf16_hi(q.z); l.z = bf16_hi(q.z - bf16_val(h.z));
    h.w = bf16_hi(q.w); l.w = bf16_hi(q.w - bf16_val(h.w));
    *(ushort4*)&Qh[dst] = h; *(ushort4*)&Ql[dst] = l;
    h.x = bf16_hi(k.x); l.x = bf16_hi(k.x - bf16_val(h.x));
    h.y = bf16_hi(k.y); l.y = bf16_hi(k.y - bf16_val(h.y));
    h.z = bf16_hi(k.z); l.z = bf16_hi(k.z - bf16_val(h.z));
    h.w = bf16_hi(k.w); l.w = bf16_hi(k.w - bf16_val(h.w));
    *(ushort4*)&Kh[dst] = h; *(ushort4*)&Kl[dst] = l;
}

// ---------------------------------------------------------------------------
// K1: base = (Q.K^T)/sqrt(128) + locality. Frag-tiled coalesced loads, no LDS.
__global__ __launch_bounds__(256) void base_mfma(
        const unsigned short* __restrict__ Qh, const unsigned short* __restrict__ Ql,
        const unsigned short* __restrict__ Kh, const unsigned short* __restrict__ Kl,
        const float* __restrict__ d_ls, float* __restrict__ base) {
    const int tid = threadIdx.x;
    const int w = tid >> 6, lane = tid & 63;
    const int quad = lane >> 4, l16 = lane & 15;
    const int b = blockIdx.z;
    const int i0 = blockIdx.y * 128, j0 = blockIdx.x * 128;
    const int trA0 = (b * NN + i0) / 16 + w * 2;   // global row-tile for A
    const int trB0 = (b * NN + j0) / 16;           // global row-tile for B

    f32x4 acc[2][8];
    #pragma unroll
    for (int a = 0; a < 2; ++a)
        #pragma unroll
        for (int c = 0; c < 8; ++c) acc[a][c] = (f32x4){0.f, 0.f, 0.f, 0.f};

    #pragma unroll
    for (int kc = 0; kc < 4; ++kc) {
        bf16x8 aH[2], aL[2];
        #pragma unroll
        for (int rt = 0; rt < 2; ++rt) {
            const size_t off = ((size_t)((trA0 + rt) * 4 + kc) * 64 + lane) * 8;
            aH[rt] = *(const bf16x8*)&Qh[off];
            aL[rt] = *(const bf16x8*)&Ql[off];
        }
        #pragma unroll
        for (int ct = 0; ct < 8; ++ct) {
            const size_t off = ((size_t)((trB0 + ct) * 4 + kc) * 64 + lane) * 8;
            bf16x8 bH = *(const bf16x8*)&Kh[off];
            bf16x8 bL = *(const bf16x8*)&Kl[off];
            #pragma unroll
            for (int rt = 0; rt < 2; ++rt) {
                acc[rt][ct] = __builtin_amdgcn_mfma_f32_16x16x32_bf16(aH[rt], bH, acc[rt][ct], 0, 0, 0);
                acc[rt][ct] = __builtin_amdgcn_mfma_f32_16x16x32_bf16(aH[rt], bL, acc[rt][ct], 0, 0, 0);
                acc[rt][ct] = __builtin_amdgcn_mfma_f32_16x16x32_bf16(aL[rt], bH, acc[rt][ct], 0, 0, 0);
            }
        }
    }
    const float ls = d_ls[0];
    const float rs = 0.08838834764831845f;  // 1/sqrt(128)
    #pragma unroll
    for (int rt = 0; rt < 2; ++rt)
        #pragma unroll
        for (int reg = 0; reg < 4; ++reg) {
            const int i = i0 + w * 32 + rt * 16 + quad * 4 + reg;
            float* brow = base + ((size_t)b * NN + i) * NN;
            #pragma unroll
            for (int ct = 0; ct < 8; ++ct) {
                const int j = j0 + ct * 16 + l16;
                const float dist = fmaxf(fabsf((float)(i - j)), 1.0f);
                brow[j] = acc[rt][ct][reg] * rs + ls / dist;
            }
        }
}

// ---------------------------------------------------------------------------
// K2 (fused): row softmax stats + column partials -> received.
// 8 rows/block (2 per wave), grid BN/8 = 1024 -> 4 blocks/CU, 16 waves/CU.
// LDS 32 KB x 4 blocks = 128 KB <= 160 KB.
template <bool WRITE_OUT>
__global__ __launch_bounds__(256) void step_pass(
        const float* __restrict__ base, const float* __restrict__ charge,
        const int t, const float* __restrict__ d_ss,
        float* __restrict__ received, float* __restrict__ out) {
    __shared__ float colsum[4][NN];
    const int tid = threadIdx.x;
    const int w = tid >> 6, lane = tid & 63;
    const int b = blockIdx.x >> 8;              // 256 blocks per batch
    const int rbase = (blockIdx.x & 255) * 8;
    const float ss = d_ss[0];
    const size_t cb = (size_t)b << 11;          // per-batch column offset

    float col_acc[32];
    #pragma unroll
    for (int q = 0; q < 32; ++q) col_acc[q] = 0.f;

    for (int rr = 0; rr < 2; ++rr) {
        const size_t ri = cb + rbase + w * 2 + rr;
        const float* row = base + ri * NN;
        float ci[4];
        for (int u = 0; u < t; ++u) ci[u] = charge[(size_t)(u + 1) * BN + ri] * ss;

        float x[32];
        float mx = -1e30f;
        #pragma unroll
        for (int k = 0; k < 8; ++k) {
            const int c = k * 256 + lane * 4;
            float4 bv = *(const float4*)&row[c];
            float m0 = 1.f, m1 = 1.f, m2 = 1.f, m3 = 1.f;
            for (int u = 0; u < t; ++u) {
                float4 cj = *(const float4*)&charge[(size_t)(u + 1) * BN + cb + c];
                m0 += ci[u] * cj.x; m1 += ci[u] * cj.y;
                m2 += ci[u] * cj.z; m3 += ci[u] * cj.w;
            }
            x[k * 4 + 0] = bv.x * m0; x[k * 4 + 1] = bv.y * m1;
            x[k * 4 + 2] = bv.z * m2; x[k * 4 + 3] = bv.w * m3;
            mx = fmaxf(mx, fmaxf(fmaxf(x[k * 4], x[k * 4 + 1]),
                                 fmaxf(x[k * 4 + 2], x[k * 4 + 3])));
        }
        #pragma unroll
        for (int off = 32; off > 0; off >>= 1) mx = fmaxf(mx, __shfl_xor(mx, off));

        float se = 0.f;
        #pragma unroll
        for (int q = 0; q < 32; ++q) { x[q] = __expf(x[q] - mx); se += x[q]; }
        #pragma unroll
        for (int off = 32; off > 0; off >>= 1) se += __shfl_xor(se, off);
        const float inv = 1.0f / se;

        if (WRITE_OUT) {
            #pragma unroll
            for (int k = 0; k < 8; ++k) {
                const int c = k * 256 + lane * 4;
                float4 o = {x[k * 4 + 0] * inv, x[k * 4 + 1] * inv,
                            x[k * 4 + 2] * inv, x[k * 4 + 3] * inv};
                *(float4*)&out[ri * NN + c] = o;
            }
        } else {
            #pragma unroll
            for (int q = 0; q < 32; ++q) col_acc[q] += x[q] * inv;
        }
    }

    if (!WRITE_OUT) {
        #pragma unroll
        for (int k = 0; k < 8; ++k) {
            const int c = k * 256 + lane * 4;
            *(float4*)&colsum[w][c] = *(float4*)&col_acc[k * 4];
        }
        __syncthreads();
        #pragma unroll
        for (int k = 0; k < 8; ++k) {
            const int c = tid + 256 * k;
            const float s = colsum[0][c] + colsum[1][c] + colsum[2][c] + colsum[3][c];
            atomicAdd(&received[cb + c], s);
        }
    }
}

// ---------------------------------------------------------------------------
// K4: c_{t+1} = c_t * (1 - decay * sigmoid(received - 1)); re-zero received.
__global__ __launch_bounds__(256) void charge_update(
        float* __restrict__ received, const float* __restrict__ d_decay,
        const float* __restrict__ c_prev, float* __restrict__ c_next) {
    const int r = blockIdx.x * 256 + threadIdx.x;
    const float recv = received[r];
    received[r] = 0.f;
    const float sg = 1.f / (1.f + __expf(1.f - recv));
    c_next[r] = c_prev[r] * (1.f - d_decay[0] * sg);
}

// ---------------------------------------------------------------------------
extern "C" void kernel_launch(void* const* d_in, const int* in_sizes, int n_in,
                              void* d_out, int out_size, void* d_ws, size_t ws_size,
                              hipStream_t stream) {
    const float* feat  = (const float*)d_in[0];
    const float* Wq    = (const float*)d_in[1];
    const float* Wk    = (const float*)d_in[2];
    const float* cw    = (const float*)d_in[3];
    const float* cb    = (const float*)d_in[4];
    const float* ls    = (const float*)d_in[5];
    const float* ssp   = (const float*)d_in[6];
    const float* decay = (const float*)d_in[7];

    float* ws   = (float*)d_ws;
    float* base = ws + BASE_OFF;
    float* partQ = ws + PARTQ_OFF;
    float* partK = ws + PARTK_OFF;
    unsigned short* Fh = (unsigned short*)(ws + FH_OFF);
    unsigned short* Fl = (unsigned short*)(ws + FL_OFF);
    unsigned short* qkhl = (unsigned short*)(ws + QKHL_OFF);
    unsigned short* Qh = qkhl;
    unsigned short* Ql = qkhl + (size_t)BN * DE;
    unsigned short* Kh = qkhl + (size_t)2 * BN * DE;
    unsigned short* Kl = qkhl + (size_t)3 * BN * DE;
    // Wsw overlays the QKHL region during phase A (dead before qk_reduce writes)
    unsigned short* Wqh = qkhl;
    unsigned short* Wql = qkhl + (size_t)DE * FD;
    unsigned short* Wkh = qkhl + (size_t)2 * DE * FD;
    unsigned short* Wkl = qkhl + (size_t)3 * DE * FD;
    float* charge = ws + C_OFF;
    float* recv   = ws + R_OFF;
    float* out    = (float*)d_out;

    convert_F<<<BN * FD / 8 / 256, 256, 0, stream>>>(feat, Fh, Fl);
    convert_W<<<dim3(64, 2), 256, 0, stream>>>(Wq, Wk, Wqh, Wql, Wkh, Wkl);
    charge_init<<<BN / 4, 256, 0, stream>>>(feat, cw, cb, charge, recv);
    qk_mfma<<<dim3(4, BN / 64), 256, 0, stream>>>(Fh, Fl, Wqh, Wql, Wkh, Wkl, partQ, partK);
    qk_reduce<<<BN * DE / 4 / 256, 256, 0, stream>>>(partQ, partK, Qh, Ql, Kh, Kl);
    base_mfma<<<dim3(NN / 128, NN / 128, NB), 256, 0, stream>>>(Qh, Ql, Kh, Kl, ls, base);

    for (int t = 0; t < 4; ++t) {
        step_pass<false><<<BN / 8, 256, 0, stream>>>(base, charge, t, ssp, recv, nullptr);
        charge_update<<<BN / 256, 256, 0, stream>>>(
            recv, decay, charge + (size_t)t * BN, charge + (size_t)(t + 1) * BN);
    }
    step_pass<true><<<BN / 8, 256, 0, stream>>>(base, charge, 4, ssp, recv, out);
}